// Round 8
// baseline (166.294 us; speedup 1.0000x reference)
//
#include <hip/hip_runtime.h>

#define EPS_W 1e-6f

__device__ __forceinline__ float fast_rsq(float x) { return __builtin_amdgcn_rsqf(x); }
__device__ __forceinline__ float fast_rcp(float x) { return __builtin_amdgcn_rcpf(x); }

// ---------------------------------------------------------------------------
// Horn-quaternion solve via 5-sweep cyclic Jacobi on N (4x4).
// IDENTICAL to round-7 verified version (absmax 0.0039).
// S[16] = { sw, Sa0..2, Sb0..2, M00,M01,M02,M10,M11,M12,M20,M21,M22 }
// ---------------------------------------------------------------------------
__device__ __forceinline__ void solve16(const float S[16], float R[9], float t[3])
{
    const float sw  = S[0];
    const float Sa0 = S[1], Sa1 = S[2], Sa2 = S[3];
    const float Sb0 = S[4], Sb1 = S[5], Sb2 = S[6];

    const float inv = fast_rcp(sw + EPS_W);
    const float cA0 = Sa0*inv, cA1 = Sa1*inv, cA2 = Sa2*inv;
    const float cB0 = Sb0*inv, cB1 = Sb1*inv, cB2 = Sb2*inv;

    float H[3][3];
    H[0][0] = S[7]  - cA0*Sb0 - Sa0*cB0 + sw*cA0*cB0;
    H[0][1] = S[8]  - cA0*Sb1 - Sa0*cB1 + sw*cA0*cB1;
    H[0][2] = S[9]  - cA0*Sb2 - Sa0*cB2 + sw*cA0*cB2;
    H[1][0] = S[10] - cA1*Sb0 - Sa1*cB0 + sw*cA1*cB0;
    H[1][1] = S[11] - cA1*Sb1 - Sa1*cB1 + sw*cA1*cB1;
    H[1][2] = S[12] - cA1*Sb2 - Sa1*cB2 + sw*cA1*cB2;
    H[2][0] = S[13] - cA2*Sb0 - Sa2*cB0 + sw*cA2*cB0;
    H[2][1] = S[14] - cA2*Sb1 - Sa2*cB1 + sw*cA2*cB1;
    H[2][2] = S[15] - cA2*Sb2 - Sa2*cB2 + sw*cA2*cB2;

    const float Sxx=H[0][0], Sxy=H[0][1], Sxz=H[0][2];
    const float Syx=H[1][0], Syy=H[1][1], Syz=H[1][2];
    const float Szx=H[2][0], Szy=H[2][1], Szz=H[2][2];

    float Nm[4][4];
    Nm[0][0] =  Sxx+Syy+Szz; Nm[0][1] = Syz-Szy;      Nm[0][2] = Szx-Sxz;      Nm[0][3] = Sxy-Syx;
    Nm[1][0] =  Nm[0][1];    Nm[1][1] = Sxx-Syy-Szz;  Nm[1][2] = Sxy+Syx;      Nm[1][3] = Szx+Sxz;
    Nm[2][0] =  Nm[0][2];    Nm[2][1] = Nm[1][2];     Nm[2][2] = -Sxx+Syy-Szz; Nm[2][3] = Syz+Szy;
    Nm[3][0] =  Nm[0][3];    Nm[3][1] = Nm[1][3];     Nm[3][2] = Nm[2][3];     Nm[3][3] = -Sxx-Syy+Szz;

    float Vv[4][4] = {{1.f,0.f,0.f,0.f},{0.f,1.f,0.f,0.f},{0.f,0.f,1.f,0.f},{0.f,0.f,0.f,1.f}};

    for (int sweep = 0; sweep < 5; ++sweep) {
        #pragma unroll
        for (int pair = 0; pair < 6; ++pair) {
            constexpr int PP[6] = {0,0,0,1,1,2};
            constexpr int QQ[6] = {1,2,3,2,3,3};
            const int p = PP[pair], q = QQ[pair];
            float d  = Nm[p][p] - Nm[q][q];
            float o  = Nm[p][q];
            float r2 = d*d + 4.f*o*o;
            bool tiny = r2 < 1e-30f;
            float rinv = fast_rsq(tiny ? 1.f : r2);
            float hh = 0.5f + 0.5f * fabsf(d) * rinv;
            float ci = fast_rsq(hh);
            float c  = hh * ci;
            float s  = (d < 0.f ? o : -o) * rinv * ci;
            c = tiny ? 1.f : c;
            s = tiny ? 0.f : s;
            #pragma unroll
            for (int k = 0; k < 4; ++k) {
                float akp = Nm[k][p], akq = Nm[k][q];
                Nm[k][p] = c*akp - s*akq;
                Nm[k][q] = s*akp + c*akq;
            }
            #pragma unroll
            for (int k = 0; k < 4; ++k) {
                float apk = Nm[p][k], aqk = Nm[q][k];
                Nm[p][k] = c*apk - s*aqk;
                Nm[q][k] = s*apk + c*aqk;
            }
            #pragma unroll
            for (int k = 0; k < 4; ++k) {
                float vkp = Vv[k][p], vkq = Vv[k][q];
                Vv[k][p] = c*vkp - s*vkq;
                Vv[k][q] = s*vkp + c*vkq;
            }
        }
    }

    float q0=Vv[0][0], q1=Vv[1][0], q2=Vv[2][0], q3=Vv[3][0];
    float best = Nm[0][0];
    #pragma unroll
    for (int m = 1; m < 4; ++m) {
        bool bt = Nm[m][m] > best;
        best = bt ? Nm[m][m] : best;
        q0 = bt ? Vv[0][m] : q0;
        q1 = bt ? Vv[1][m] : q1;
        q2 = bt ? Vv[2][m] : q2;
        q3 = bt ? Vv[3][m] : q3;
    }
    float qn = fast_rsq(q0*q0 + q1*q1 + q2*q2 + q3*q3);
    q0*=qn; q1*=qn; q2*=qn; q3*=qn;

    float R00 = q0*q0+q1*q1-q2*q2-q3*q3;
    float R01 = 2.f*(q1*q2 - q0*q3);
    float R02 = 2.f*(q1*q3 + q0*q2);
    float R10 = 2.f*(q1*q2 + q0*q3);
    float R11 = q0*q0-q1*q1+q2*q2-q3*q3;
    float R12 = 2.f*(q2*q3 - q0*q1);
    float R20 = 2.f*(q1*q3 - q0*q2);
    float R21 = 2.f*(q2*q3 + q0*q1);
    float R22 = q0*q0-q1*q1-q2*q2+q3*q3;

    float trRH  = R00*Sxx+R01*Syx+R02*Szx
                + R10*Sxy+R11*Syy+R12*Szy
                + R20*Sxz+R21*Syz+R22*Szz;
    float trRtH = R00*Sxx+R01*Sxy+R02*Sxz
                + R10*Syx+R11*Syy+R12*Syz
                + R20*Szx+R21*Szy+R22*Szz;
    if (trRtH > trRH) {
        float tt;
        tt = R01; R01 = R10; R10 = tt;
        tt = R02; R02 = R20; R20 = tt;
        tt = R12; R12 = R21; R21 = tt;
    }

    R[0]=R00; R[1]=R01; R[2]=R02;
    R[3]=R10; R[4]=R11; R[5]=R12;
    R[6]=R20; R[7]=R21; R[8]=R22;
    t[0] = cB0 - (R00*cA0 + R01*cA1 + R02*cA2);
    t[1] = cB1 - (R10*cA0 + R11*cA1 + R12*cA2);
    t[2] = cB2 - (R20*cA0 + R21*cA1 + R22*cA2);
}

// ---------------------------------------------------------------------------
// n==20 kernel, 256 threads / 64 items per block, LDS-staged.
//  Phase A: fully lane-coalesced float4 global loads (kills the TA address-
//           divergence of the strided per-lane pattern), scalar LDS stores
//           into odd-stride (61/21 float) per-item rows (stride coprime to
//           32 banks -> phase-B reads conflict-free).
//  Phase B: thread i accumulates+solves item i entirely from LDS.
//  Phase C: output staged through LDS -> 1 coalesced float4 store/thread.
// ---------------------------------------------------------------------------
#define ITEMS_PB 64

__global__ __launch_bounds__(256) void kabsch_lds20_kernel(
    const float* __restrict__ A, const float* __restrict__ B,
    const float* __restrict__ W, float* __restrict__ Out, int bs)
{
    __shared__ float sA[ITEMS_PB * 61];   // 60 used + 1 pad
    __shared__ float sB[ITEMS_PB * 61];
    __shared__ float sW[ITEMS_PB * 21];   // 20 used + 1 pad
    __shared__ float sO[ITEMS_PB * 17];   // 16 used + 1 pad

    const int tid = threadIdx.x;
    const int blk = blockIdx.x;
    const int base_item = blk * ITEMS_PB;
    int itemcnt = bs - base_item;
    if (itemcnt > ITEMS_PB) itemcnt = ITEMS_PB;

    // ---- Phase A: coalesced staging ----
    const float4* Ag = reinterpret_cast<const float4*>(A) + (size_t)base_item * 15;
    const float4* Bg = reinterpret_cast<const float4*>(B) + (size_t)base_item * 15;
    const float4* Wg = reinterpret_cast<const float4*>(W) + (size_t)base_item * 5;

    const int nf4 = itemcnt * 15;                 // A/B float4 count
    for (int j = tid; j < nf4; j += 256) {
        const int it = j / 15;
        const int wi = j - it * 15;
        float4 v = Ag[j];
        float* d = &sA[it * 61 + wi * 4];
        d[0] = v.x; d[1] = v.y; d[2] = v.z; d[3] = v.w;
        float4 u = Bg[j];
        float* e = &sB[it * 61 + wi * 4];
        e[0] = u.x; e[1] = u.y; e[2] = u.z; e[3] = u.w;
    }
    const int nw4 = itemcnt * 5;                  // W float4 count
    for (int j = tid; j < nw4; j += 256) {
        const int it = j / 5;
        const int wi = j - it * 5;
        float4 v = Wg[j];
        float* d = &sW[it * 21 + wi * 4];
        d[0] = v.x; d[1] = v.y; d[2] = v.z; d[3] = v.w;
    }
    __syncthreads();

    // ---- Phase B: per-item accumulate + solve from LDS ----
    if (tid < itemcnt) {
        const float* a = &sA[tid * 61];
        const float* b = &sB[tid * 61];
        const float* w = &sW[tid * 21];

        float S[16];
        #pragma unroll
        for (int k = 0; k < 16; ++k) S[k] = 0.f;

        #pragma unroll
        for (int p = 0; p < 20; ++p) {
            float wv = w[p];
            wv = wv < 0.f ? 0.f : wv;
            float ax = a[3*p+0], ay = a[3*p+1], az = a[3*p+2];
            float bx = b[3*p+0], by = b[3*p+1], bz = b[3*p+2];
            S[0] += wv;
            float wax = wv*ax, way = wv*ay, waz = wv*az;
            S[1] += wax; S[2] += way; S[3] += waz;
            S[4] += wv*bx; S[5] += wv*by; S[6] += wv*bz;
            S[7]  += wax*bx; S[8]  += wax*by; S[9]  += wax*bz;
            S[10] += way*bx; S[11] += way*by; S[12] += way*bz;
            S[13] += waz*bx; S[14] += waz*by; S[15] += waz*bz;
        }

        float R[9], t[3];
        solve16(S, R, t);

        float* o = &sO[tid * 17];
        o[0]=R[0];  o[1]=R[1];  o[2]=R[2];  o[3]=t[0];
        o[4]=R[3];  o[5]=R[4];  o[6]=R[5];  o[7]=t[1];
        o[8]=R[6];  o[9]=R[7];  o[10]=R[8]; o[11]=t[2];
        o[12]=0.f;  o[13]=0.f;  o[14]=0.f;  o[15]=1.f;
    }
    __syncthreads();

    // ---- Phase C: coalesced output write (1 float4 per thread) ----
    const int no4 = itemcnt * 4;                  // output float4 count
    float4* Og = reinterpret_cast<float4*>(Out) + (size_t)base_item * 4;
    for (int j = tid; j < no4; j += 256) {
        const int it = j >> 2;
        const int wi = j & 3;
        const float* o = &sO[it * 17 + wi * 4];
        Og[j] = make_float4(o[0], o[1], o[2], o[3]);
    }
}

// ---------------------------------------------------------------------------
// Generic fallback (any n): 1 thread per item, scalar loads.
// ---------------------------------------------------------------------------
__global__ __launch_bounds__(256) void kabsch_generic_kernel(
    const float* __restrict__ A, const float* __restrict__ B,
    const float* __restrict__ W, float* __restrict__ Out,
    int bs, int n)
{
    const int b = blockIdx.x * blockDim.x + threadIdx.x;
    if (b >= bs) return;

    float S[16];
    #pragma unroll
    for (int k = 0; k < 16; ++k) S[k] = 0.f;

    for (int j = 0; j < n; ++j) {
        const float* ap = A + ((size_t)b * n + j) * 3;
        const float* bp = B + ((size_t)b * n + j) * 3;
        float w = W[(size_t)b * n + j];
        w = w < 0.f ? 0.f : w;
        float ax=ap[0], ay=ap[1], az=ap[2];
        float bx=bp[0], by=bp[1], bz=bp[2];
        S[0] += w;
        float wax = w*ax, way = w*ay, waz = w*az;
        S[1] += wax; S[2] += way; S[3] += waz;
        S[4] += w*bx; S[5] += w*by; S[6] += w*bz;
        S[7] += wax*bx; S[8]  += wax*by; S[9]  += wax*bz;
        S[10]+= way*bx; S[11] += way*by; S[12] += way*bz;
        S[13]+= waz*bx; S[14] += waz*by; S[15] += waz*bz;
    }

    float R[9], t[3];
    solve16(S, R, t);

    float4* O4 = reinterpret_cast<float4*>(Out + (size_t)b * 16);
    O4[0] = make_float4(R[0], R[1], R[2], t[0]);
    O4[1] = make_float4(R[3], R[4], R[5], t[1]);
    O4[2] = make_float4(R[6], R[7], R[8], t[2]);
    O4[3] = make_float4(0.f, 0.f, 0.f, 1.f);
}

extern "C" void kernel_launch(void* const* d_in, const int* in_sizes, int n_in,
                              void* d_out, int out_size, void* d_ws, size_t ws_size,
                              hipStream_t stream) {
    const float* A = (const float*)d_in[0];
    const float* B = (const float*)d_in[1];
    const float* W = (const float*)d_in[2];
    float* Out = (float*)d_out;
    const int bs = out_size / 16;
    const int n  = (bs > 0) ? (in_sizes[2] / bs) : 0;
    if (n == 20) {
        const int blocks = (bs + ITEMS_PB - 1) / ITEMS_PB;
        hipLaunchKernelGGL(kabsch_lds20_kernel, dim3(blocks), dim3(256), 0, stream,
                           A, B, W, Out, bs);
    } else {
        const int blocks = (bs + 255) / 256;
        hipLaunchKernelGGL(kabsch_generic_kernel, dim3(blocks), dim3(256), 0, stream,
                           A, B, W, Out, bs, n);
    }
}